// Round 5
// baseline (190.515 us; speedup 1.0000x reference)
//
#include <hip/hip_runtime.h>

// Problem constants: B=8, C=3, T=16, H=W=224, P0=2, P=16, FC=2
#define Bd 8
#define Cd 3
#define Td 16
#define Hd 224
#define Wd 224
#define Nd 1568                 // (T/2)*(H/16)*(W/16)
#define HWd (Hd*Wd)             // 50176
#define NTOK (Bd*Nd)            // 12544 flat tokens
#define GRID_MAIN (NTOK*2)      // 25088: one block per (token, time-slice)
#define PATCH_ELEMS 1536.0

// ---------------- main: one block per (masked token, slice) ---------------
// No LDS staging, no barriers: raw is L3-resident (77 MB < 256 MB) and each
// token's bilinear tap window has high L1 locality (~9 KB unique/block).
// 256 threads = 256 pixels; each thread computes weights once and gathers
// 4 taps + target for all 3 channels (12 independent loads -> deep MLP).
// Unmasked tokens exit after one scalar load (~half the grid).
__global__ __launch_bounds__(256, 8)
void flow_mse_gather(const float* __restrict__ outp,
                     const float* __restrict__ raw,
                     const int* __restrict__ mask,
                     float* __restrict__ partial) {
    const int tid = threadIdx.x;
    const int bid = blockIdx.x;
    const int ft  = bid >> 1;             // flat token (b*Nd + n)
    const int i0  = bid & 1;

    if (mask[ft] == 0) {                  // block-uniform scalar branch
        if (tid == 0) partial[bid] = 0.f;
        return;
    }

    const int b  = ft / Nd;
    const int n  = ft - b * Nd;
    const int t2 = n / 196;
    const int rm = n - t2 * 196;
    const int ph = rm / 14;
    const int pw = rm - ph * 14;
    const int t  = (t2 << 1) | i0;

    const int py = tid >> 4, px = tid & 15;
    const int h  = (ph << 4) + py;
    const int w  = (pw << 4) + px;

    // flow (map_x, map_y) for this pixel: d = (i0<<9) + (py<<5) + (px<<1) + fc
    const float2 f = ((const float2*)(outp + ((size_t)ft << 10) + (i0 << 9)))[tid];

    const float mx = f.x + (float)w;
    const float my = f.y + (float)h;
    const float x0 = floorf(mx), y0 = floorf(my);
    const float wx = mx - x0,    wy = my - y0;
    const int x0i = (int)x0, y0i = (int)y0;
    const int x1i = x0i + 1,  y1i = y0i + 1;

    const bool vx0 = (x0i >= 0) && (x0i < Wd);
    const bool vx1 = (x1i >= 0) && (x1i < Wd);
    const bool vy0 = (y0i >= 0) && (y0i < Hd);
    const bool vy1 = (y1i >= 0) && (y1i < Hd);

    const float W00 = (1.f - wx) * (1.f - wy) * ((vx0 && vy0) ? 1.f : 0.f);
    const float W01 = wx         * (1.f - wy) * ((vx1 && vy0) ? 1.f : 0.f);
    const float W10 = (1.f - wx) * wy         * ((vx0 && vy1) ? 1.f : 0.f);
    const float W11 = wx         * wy         * ((vx1 && vy1) ? 1.f : 0.f);

    const int xc0 = min(max(x0i, 0), Wd - 1);
    const int xc1 = min(max(x1i, 0), Wd - 1);
    const int yc0 = min(max(y0i, 0), Hd - 1);
    const int yc1 = min(max(y1i, 0), Hd - 1);

    // tap + target offsets shared across the 3 channels
    const int i00 = yc0 * Wd + xc0;
    const int i01 = yc0 * Wd + xc1;
    const int i10 = yc1 * Wd + xc0;
    const int i11 = yc1 * Wd + xc1;
    const int itg = h * Wd + w;

    const float* base = raw + (size_t)(b * (Cd * Td) + t) * HWd;  // + c*16*HWd
    float acc = 0.f;
    #pragma unroll
    for (int c = 0; c < Cd; ++c) {
        const float* img = base + (size_t)c * (Td * HWd);
        float rec = img[i00] * W00 + img[i01] * W01
                  + img[i10] * W10 + img[i11] * W11;
        float d = rec - img[itg];
        acc += d * d;
    }

    // block reduce: 4 waves of 64
    __shared__ float sred[4];
    for (int off = 32; off > 0; off >>= 1) acc += __shfl_down(acc, off, 64);
    if ((tid & 63) == 0) sred[tid >> 6] = acc;
    __syncthreads();
    if (tid == 0) partial[bid] = sred[0] + sred[1] + sred[2] + sred[3];
}

// ---------------- finalize: reduce partials, count mask directly ----------
__global__ void finalize_kernel(const float* __restrict__ partial,
                                const int* __restrict__ mask,
                                float* __restrict__ out) {
    const int tid = threadIdx.x;
    double s = 0.0;
    for (int i = tid; i < GRID_MAIN; i += 256) s += (double)partial[i];
    int c = 0;
    for (int i = tid; i < NTOK; i += 256) c += (mask[i] != 0) ? 1 : 0;
    for (int off = 32; off > 0; off >>= 1) {
        s += __shfl_down(s, off, 64);
        c += __shfl_down(c, off, 64);
    }
    __shared__ double sd[4];
    __shared__ int    sc[4];
    int lane = tid & 63, wid = tid >> 6;
    if (lane == 0) { sd[wid] = s; sc[wid] = c; }
    __syncthreads();
    if (tid == 0) {
        double st = sd[0] + sd[1] + sd[2] + sd[3];
        int    ct = sc[0] + sc[1] + sc[2] + sc[3];
        double denom = (double)(ct > 0 ? ct : 1) * PATCH_ELEMS;
        out[0] = (float)(st / denom);
    }
}

extern "C" void kernel_launch(void* const* d_in, const int* in_sizes, int n_in,
                              void* d_out, int out_size, void* d_ws, size_t ws_size,
                              hipStream_t stream) {
    const float* outp = (const float*)d_in[0];   // (B,N,D) fp32 flow tokens
    const float* raw  = (const float*)d_in[1];   // (B,C,T,H,W) fp32
    const int*   mask = (const int*)d_in[2];     // (B,N)
    float* out = (float*)d_out;

    // ws layout: partial[GRID_MAIN] floats (every block writes its slot ->
    // no zero-init of the poisoned workspace needed)
    float* partial = (float*)d_ws;

    flow_mse_gather<<<GRID_MAIN, 256, 0, stream>>>(outp, raw, mask, partial);
    finalize_kernel<<<1, 256, 0, stream>>>(partial, mask, out);
}